// Round 23
// baseline (74.030 us; speedup 1.0000x reference)
//
#include <hip/hip_runtime.h>
#include <hip/hip_bf16.h>

#define NB   32
#define CIN  128
#define COUT 256
#define HH   56
#define WW   56
#define CH   59        // padded B-row length in 16B chunks (944 = 16*59)

typedef __attribute__((ext_vector_type(8))) short short8;   // 8 bf16 (4 VGPRs)
typedef __attribute__((ext_vector_type(4))) float f32x4;    // MFMA accumulator

// round-to-nearest-even fp32 -> bf16 (raw u16)
__device__ __forceinline__ unsigned short f2bf(float f) {
    unsigned int u = __builtin_bit_cast(unsigned int, f);
    u = u + 0x7fffu + ((u >> 16) & 1u);
    return (unsigned short)(u >> 16);
}

// async global->LDS, 16B per lane; LDS dest = wave-uniform base + lane*16
__device__ __forceinline__ void glds16(const unsigned short* g, unsigned short* l) {
    __builtin_amdgcn_global_load_lds(
        (const __attribute__((address_space(1))) unsigned int*)g,
        (__attribute__((address_space(3))) unsigned int*)l,
        16, 0, 0);
}

// ---------------------------------------------------------------------------
// Pre-pass (LDS-staged + parallel): weights OIHW f32 -> wt2 in EXACT MFMA
// A-fragment order:
//   chunk ((s*16 + f)*64 + lane), elem j:  w[o=f*16+r][c=cc*32+g*8+j][tap t]
//   (s = K-step: t = s>>2, cc = s&3;  lane = g*16 + r)
// 64 blocks = (fragment f, row-quarter rq): each reads a CONTIGUOUS 4-row
// 18 KB f32 slab with coalesced float4 loads into LDS (row stride 1153),
// then emits uint4 chunks for its 4 r-values (64 B-contiguous runs).
// r22's 16-block version starved launch parallelism (16/256 CUs -> ~6 us);
// this uses 64 CUs and stays fully coalesced on the read side.
// ---------------------------------------------------------------------------
__global__ __launch_bounds__(256) void wpose_kernel(const float* __restrict__ w,
                                                    unsigned short* __restrict__ wt2) {
    __shared__ float lw[4 * 1153];          // 18448 B
    const int tid = threadIdx.x;
    const int f   = blockIdx.x >> 2;        // fragment 0..15
    const int rq  = blockIdx.x & 3;         // row-quarter 0..3
    const float* src = w + ((size_t)f * 16 + rq * 4) * 1152;

    // coalesced read: 1152 float4 over 256 threads
    for (int i4 = tid; i4 < 1152; i4 += 256) {
        float4 v = *(const float4*)(src + 4 * i4);
        int op   = i4 / 288;                // row within slab (288 f4/row)
        int pos4 = i4 - op * 288;
        float* d = &lw[op * 1153 + 4 * pos4];
        d[0] = v.x; d[1] = v.y; d[2] = v.z; d[3] = v.w;
    }
    __syncthreads();

    // emit: 576 units = 36 s x 4 g x 4 rr;  u = (s*4 + g)*4 + rr
    for (int u = tid; u < 576; u += 256) {
        int rr = u & 3;
        int g  = (u >> 2) & 3;
        int s  = u >> 4;
        int t  = s >> 2, cc = s & 3;
        const float* p = &lw[rr * 1153 + (cc * 32 + g * 8) * 9 + t];
        uint4 q;
        q.x = (unsigned)f2bf(p[0])  | ((unsigned)f2bf(p[9])  << 16);
        q.y = (unsigned)f2bf(p[18]) | ((unsigned)f2bf(p[27]) << 16);
        q.z = (unsigned)f2bf(p[36]) | ((unsigned)f2bf(p[45]) << 16);
        q.w = (unsigned)f2bf(p[54]) | ((unsigned)f2bf(p[63]) << 16);
        int lane = g * 16 + rq * 4 + rr;
        *(uint4*)&wt2[((size_t)(s * 16 + f) * 64 + lane) * 8] = q;
    }
}

// ---------------------------------------------------------------------------
// Main conv (= r20/r21 measured-best, UNCHANGED):
// block = 256 Cout x 224 spatial (4 output rows h0..h0+3), 512 threads =
// 8 waves as 4(M) x 2(N); wave = 64 Cout x 112 cols (4 M-frags x 7 N-frags
// of 16x16x32 -- the unique port-balanced point at 2 waves/SIMD).
// 36 K-steps, barrier-free.
//
// T1 swizzle: 1-D grid of 448 (= 8*56 -> bijective); XCD d%8 gets 56
// consecutive tiles = 4 complete images -> halo rows + weight stream
// are L2-local (measured: FETCH 43.2 -> 30.2 MB, -2.3 us).
//
//   A: per-wave private LDS ring (2 slots x 4 frags) fed by global_load_lds,
//      ordered by per-wave `s_waitcnt vmcnt(4)` only -- NO s_barrier.
//   B: x rows h0-1..h0+4 transposed in-block, float4-vectorized, staged ONCE:
//      chunk ((row*16+gc)*59 + wpos), 8 ch; wpos 0/57/58 + OOB rows zeroed
//      (pad-only zeroing). All K-loop B addressing = 16-bit ds_read imms.
//   + distance-1 B-register double-buffer.
// LDS = 90624 (B) + 65536 (A-ring) = 156160 B.
// ---------------------------------------------------------------------------
__global__ __launch_bounds__(512, 2) void conv_mfma_kernel(
        const float* __restrict__ x,
        const unsigned short* __restrict__ wt2,
        const float* __restrict__ bias,
        float* __restrict__ out) {
    __shared__ unsigned short ldsB[6 * 16 * CH * 8];    // 90624 B
    __shared__ unsigned short ldsA[8 * 2 * 2048];       // 65536 B: [wave][slot][4KB]

    const int tid  = threadIdx.x;
    // ---- XCD-chunked bijective swizzle (448 = 8 XCDs x 56 tiles) ----
    const int bid  = blockIdx.x;
    const int swz  = (bid & 7) * 56 + (bid >> 3);
    const int n    = swz / 14;
    const int h0   = (swz - n * 14) * 4;
    const int wid  = tid >> 6, lane = tid & 63;
    const int wm   = wid >> 1, wn = wid & 1;            // 4M x 2N wave grid
    const int g    = lane >> 4, r = lane & 15;

    const uint4 z = {0u, 0u, 0u, 0u};

    // ---- zero ONLY pad chunks (wpos 0,57,58 all rows) + OOB rows ----
    if (tid < 288) {                        // 6 rows x 16 gc x {0,57,58}
        int row = tid / 48, sub = tid % 48;
        int gc = sub / 3, k3 = sub % 3;
        int wp = (k3 == 0) ? 0 : (56 + k3);
        *(uint4*)&ldsB[(size_t)((row * 16 + gc) * CH + wp) * 8] = z;
    }
    if (h0 == 0) {                          // input row h0-1 OOB -> row 0 = 0
        for (int i = tid; i < 16 * CH; i += 512)
            *(uint4*)&ldsB[(size_t)i * 8] = z;
    }
    if (h0 == 52) {                         // input row h0+4 OOB -> row 5 = 0
        for (int i = tid; i < 16 * CH; i += 512)
            *(uint4*)&ldsB[(size_t)(5 * 16 * CH + i) * 8] = z;
    }

    // ---- fused transpose, float4-vectorized: unit = (row, cp, w4) ----
    {
        const float* xn = x + (size_t)n * CIN * HH * WW;
        for (int i = tid; i < 6 * 64 * 14; i += 512) {   // 5376 units
            int w4  = i % 14;
            int t1  = i / 14;
            int cp  = t1 & 63;                  // channel pair: c = 2cp, 2cp+1
            int row = t1 >> 6;                  // 0..5 -> input row h0+row-1
            int hs  = h0 + row - 1;
            if ((unsigned)hs < HH) {
                const float* p = xn + ((size_t)(2 * cp) * HH + hs) * WW + 4 * w4;
                float4 va = *(const float4*)p;
                float4 vb = *(const float4*)(p + HH * WW);
                int gc = cp >> 2, e = cp & 3;
                #pragma unroll
                for (int j = 0; j < 4; ++j) {
                    int wpos = 4 * w4 + j + 1;
                    unsigned int pk = (unsigned int)f2bf(((const float*)&va)[j])
                                    | ((unsigned int)f2bf(((const float*)&vb)[j]) << 16);
                    ((unsigned int*)ldsB)[((row * 16 + gc) * CH + wpos) * 4 + e] = pk;
                }
            }
        }
    }

    // ---- A-ring stage: wave wid's 4 frags (f = wm*4+mi) for step s -> slot ----
    unsigned short* aslot = &ldsA[(size_t)wid * 2 * 2048];
    #define STAGE_A(slot, s)                                                    \
        {                                                                       \
            const unsigned short* asrc_ =                                       \
                wt2 + ((size_t)(s) * 16 + wm * 4) * 512 + lane * 8;             \
            unsigned short* adst_ = aslot + (slot) * 2048;                      \
            glds16(asrc_,        adst_);                                        \
            glds16(asrc_ + 512,  adst_ + 512);                                  \
            glds16(asrc_ + 1024, adst_ + 1024);                                 \
            glds16(asrc_ + 1536, adst_ + 1536);                                 \
        }

    STAGE_A(0, 0);
    __syncthreads();    // drains transpose writes AND slot-0 glds; last barrier

    // per-lane B base pointers for the 7 N-fragments
    const unsigned short* bbase[7];
    #pragma unroll
    for (int ni = 0; ni < 7; ++ni) {
        int c  = ni * 16 + r;
        int hr = (c >= 56) ? 1 : 0;
        int lo = hr * (16 * CH) + (c - hr * 56);
        bbase[ni] = &ldsB[(size_t)((wn * 32 + g) * CH + lo) * 8];
    }

    f32x4 acc[4][7];
    #pragma unroll
    for (int mi = 0; mi < 4; ++mi)
        #pragma unroll
        for (int ni = 0; ni < 7; ++ni)
            #pragma unroll
            for (int v = 0; v < 4; ++v) acc[mi][ni][v] = 0.f;

    const unsigned short* aread = aslot + lane * 8;   // + slot*2048 + mi*512

    // ---- distance-1 B-register double-buffer ----
    short8 bcur[7], bnxt[7];
    #define LOAD_B(dst, s_)                                                     \
        {                                                                       \
            const int t_ = (s_) >> 2, cc_ = (s_) & 3;                           \
            const int kh_ = t_ / 3, kw_ = t_ - 3 * (t_ / 3);                    \
            const int boff_ = kh_ * 15104 + cc_ * 3776 + kw_ * 16;              \
            _Pragma("unroll")                                                   \
            for (int ni = 0; ni < 7; ++ni)                                      \
                dst[ni] = *(const short8*)((const char*)bbase[ni] + boff_);     \
        }

    LOAD_B(bcur, 0);

    #pragma unroll
    for (int s = 0; s < 36; ++s) {
        const int p = s & 1;

        if (s < 35) STAGE_A(p ^ 1, s + 1);      // next A slice (async glds)
        if (s < 35) {                           // next B frags (ds_reads issue
            if (p == 0) { LOAD_B(bnxt, s + 1); }//  before this step's MFMAs)
            else        { LOAD_B(bcur, s + 1); }
        }

        // wait: step-s's 4 glds landed (s+1's 4 may stay in flight)
        if (s < 35) asm volatile("s_waitcnt vmcnt(4)" ::: "memory");
        else        asm volatile("s_waitcnt vmcnt(0)" ::: "memory");

        short8 a[4];
        #pragma unroll
        for (int mi = 0; mi < 4; ++mi)
            a[mi] = *(const short8*)(aread + p * 2048 + mi * 512);

        #pragma unroll
        for (int mi = 0; mi < 4; ++mi)
            #pragma unroll
            for (int ni = 0; ni < 7; ++ni)
                acc[mi][ni] = __builtin_amdgcn_mfma_f32_16x16x32_bf16(
                    a[mi], (p == 0) ? bcur[ni] : bnxt[ni], acc[mi][ni], 0, 0, 0);
    }

    // ---- epilogue: D col = r (spatial), row = g*4+v (Cout within frag) ----
    #pragma unroll
    for (int mi = 0; mi < 4; ++mi) {
        const int o0 = wm * 64 + mi * 16 + 4 * g;
        const float4 bv = *(const float4*)&bias[o0];
        #pragma unroll
        for (int ni = 0; ni < 7; ++ni) {
            const int c  = ni * 16 + r;
            const int hr = (c >= 56) ? 1 : 0;
            const int h  = h0 + wn * 2 + hr;
            const int w  = c - hr * 56;
            #pragma unroll
            for (int v = 0; v < 4; ++v) {
                out[((size_t)(n * COUT + o0 + v) * HH + h) * WW + w] =
                    acc[mi][ni][v] + ((const float*)&bv)[v];
            }
        }
    }
}

extern "C" void kernel_launch(void* const* d_in, const int* in_sizes, int n_in,
                              void* d_out, int out_size, void* d_ws, size_t ws_size,
                              hipStream_t stream) {
    const float* x  = (const float*)d_in[0];   // (32,128,56,56)
    const float* wk = (const float*)d_in[1];   // (256,128,3,3)
    const float* b  = (const float*)d_in[2];   // (256,)
    float* out = (float*)d_out;

    unsigned short* wt2 = (unsigned short*)d_ws;   // 294,912 elems = 590 KB

    wpose_kernel<<<64, 256, 0, stream>>>(wk, wt2);  // (fragment, row-quarter)
    conv_mfma_kernel<<<448, 512, 0, stream>>>(x, wt2, b, out);
    (void)ws_size; (void)in_sizes; (void)n_in; (void)out_size;
}

// Round 24
// 70.356 us; speedup vs baseline: 1.0522x; 1.0522x over previous
//
#include <hip/hip_runtime.h>
#include <hip/hip_bf16.h>

#define NB   32
#define CIN  128
#define COUT 256
#define HH   56
#define WW   56
#define CH   59        // padded B-row length in 16B chunks (944 = 16*59)

typedef __attribute__((ext_vector_type(8))) short short8;   // 8 bf16 (4 VGPRs)
typedef __attribute__((ext_vector_type(4))) float f32x4;    // MFMA accumulator

// round-to-nearest-even fp32 -> bf16 (raw u16)
__device__ __forceinline__ unsigned short f2bf(float f) {
    unsigned int u = __builtin_bit_cast(unsigned int, f);
    u = u + 0x7fffu + ((u >> 16) & 1u);
    return (unsigned short)(u >> 16);
}

// async global->LDS, 16B per lane; LDS dest = wave-uniform base + lane*16
__device__ __forceinline__ void glds16(const unsigned short* g, unsigned short* l) {
    __builtin_amdgcn_global_load_lds(
        (const __attribute__((address_space(1))) unsigned int*)g,
        (__attribute__((address_space(3))) unsigned int*)l,
        16, 0, 0);
}

// ---------------------------------------------------------------------------
// Pre-pass (ORIGINAL scalar form -- measured best): weights OIHW f32 -> wt2
// in EXACT MFMA A-fragment order:
//   chunk ((s*16 + f)*64 + lane), elem j:  w[o=f*16+r][c=cc*32+g*8+j][tap t]
//   (s = K-step: t = s>>2, cc = s&3;  lane: g = lane>>4, r = lane&15)
// Output index q is LINEAR -> 2B stores perfectly coalesced; strided reads
// are L2-absorbed (each line fully consumed by neighbor threads); 1152
// blocks give full-machine TLP. LDS-staged rewrites (r22: 16 blk, r23:
// 64 blk) both measured ~3.5 us SLOWER -- parallelism beats coalescing here.
// ---------------------------------------------------------------------------
__global__ __launch_bounds__(256) void wpose_kernel(const float* __restrict__ w,
                                                    unsigned short* __restrict__ wt2) {
    int q = blockIdx.x * 256 + threadIdx.x;
    if (q >= 36 * 16 * 64 * 8) return;
    int j = q & 7;
    int l = (q >> 3) & 63;
    int f = (q >> 9) & 15;
    int s = q >> 13;
    int g = l >> 4, r = l & 15;
    int t = s >> 2, cc = s & 3;
    int o = f * 16 + r;
    int c = cc * 32 + g * 8 + j;
    wt2[q] = f2bf(w[((size_t)o * CIN + c) * 9 + t]);
}

// ---------------------------------------------------------------------------
// Main conv (= r21 measured-best, 70.30 us total):
// block = 256 Cout x 224 spatial (4 output rows h0..h0+3), 512 threads =
// 8 waves as 4(M) x 2(N); wave = 64 Cout x 112 cols (4 M-frags x 7 N-frags
// of 16x16x32 -- the unique port-balanced point at 2 waves/SIMD).
// 36 K-steps, barrier-free.
//
// T1 swizzle: 1-D grid of 448 (= 8*56 -> bijective); XCD d%8 gets 56
// consecutive tiles = 4 complete images -> halo rows + weight stream
// are L2-local (measured: FETCH 43.2 -> 30.2 MB, -2.3 us).
//
//   A: per-wave private LDS ring (2 slots x 4 frags) fed by global_load_lds,
//      ordered by per-wave `s_waitcnt vmcnt(4)` only -- NO s_barrier.
//   B: x rows h0-1..h0+4 transposed in-block, float4-vectorized, staged ONCE:
//      chunk ((row*16+gc)*59 + wpos), 8 ch; wpos 0/57/58 + OOB rows zeroed
//      (pad-only zeroing). All K-loop B addressing = 16-bit ds_read imms.
//   + distance-1 B-register double-buffer.
// LDS = 90624 (B) + 65536 (A-ring) = 156160 B.
// ---------------------------------------------------------------------------
__global__ __launch_bounds__(512, 2) void conv_mfma_kernel(
        const float* __restrict__ x,
        const unsigned short* __restrict__ wt2,
        const float* __restrict__ bias,
        float* __restrict__ out) {
    __shared__ unsigned short ldsB[6 * 16 * CH * 8];    // 90624 B
    __shared__ unsigned short ldsA[8 * 2 * 2048];       // 65536 B: [wave][slot][4KB]

    const int tid  = threadIdx.x;
    // ---- XCD-chunked bijective swizzle (448 = 8 XCDs x 56 tiles) ----
    const int bid  = blockIdx.x;
    const int swz  = (bid & 7) * 56 + (bid >> 3);
    const int n    = swz / 14;
    const int h0   = (swz - n * 14) * 4;
    const int wid  = tid >> 6, lane = tid & 63;
    const int wm   = wid >> 1, wn = wid & 1;            // 4M x 2N wave grid
    const int g    = lane >> 4, r = lane & 15;

    const uint4 z = {0u, 0u, 0u, 0u};

    // ---- zero ONLY pad chunks (wpos 0,57,58 all rows) + OOB rows ----
    if (tid < 288) {                        // 6 rows x 16 gc x {0,57,58}
        int row = tid / 48, sub = tid % 48;
        int gc = sub / 3, k3 = sub % 3;
        int wp = (k3 == 0) ? 0 : (56 + k3);
        *(uint4*)&ldsB[(size_t)((row * 16 + gc) * CH + wp) * 8] = z;
    }
    if (h0 == 0) {                          // input row h0-1 OOB -> row 0 = 0
        for (int i = tid; i < 16 * CH; i += 512)
            *(uint4*)&ldsB[(size_t)i * 8] = z;
    }
    if (h0 == 52) {                         // input row h0+4 OOB -> row 5 = 0
        for (int i = tid; i < 16 * CH; i += 512)
            *(uint4*)&ldsB[(size_t)(5 * 16 * CH + i) * 8] = z;
    }

    // ---- fused transpose, float4-vectorized: unit = (row, cp, w4) ----
    {
        const float* xn = x + (size_t)n * CIN * HH * WW;
        for (int i = tid; i < 6 * 64 * 14; i += 512) {   // 5376 units
            int w4  = i % 14;
            int t1  = i / 14;
            int cp  = t1 & 63;                  // channel pair: c = 2cp, 2cp+1
            int row = t1 >> 6;                  // 0..5 -> input row h0+row-1
            int hs  = h0 + row - 1;
            if ((unsigned)hs < HH) {
                const float* p = xn + ((size_t)(2 * cp) * HH + hs) * WW + 4 * w4;
                float4 va = *(const float4*)p;
                float4 vb = *(const float4*)(p + HH * WW);
                int gc = cp >> 2, e = cp & 3;
                #pragma unroll
                for (int j = 0; j < 4; ++j) {
                    int wpos = 4 * w4 + j + 1;
                    unsigned int pk = (unsigned int)f2bf(((const float*)&va)[j])
                                    | ((unsigned int)f2bf(((const float*)&vb)[j]) << 16);
                    ((unsigned int*)ldsB)[((row * 16 + gc) * CH + wpos) * 4 + e] = pk;
                }
            }
        }
    }

    // ---- A-ring stage: wave wid's 4 frags (f = wm*4+mi) for step s -> slot ----
    unsigned short* aslot = &ldsA[(size_t)wid * 2 * 2048];
    #define STAGE_A(slot, s)                                                    \
        {                                                                       \
            const unsigned short* asrc_ =                                       \
                wt2 + ((size_t)(s) * 16 + wm * 4) * 512 + lane * 8;             \
            unsigned short* adst_ = aslot + (slot) * 2048;                      \
            glds16(asrc_,        adst_);                                        \
            glds16(asrc_ + 512,  adst_ + 512);                                  \
            glds16(asrc_ + 1024, adst_ + 1024);                                 \
            glds16(asrc_ + 1536, adst_ + 1536);                                 \
        }

    STAGE_A(0, 0);
    __syncthreads();    // drains transpose writes AND slot-0 glds; last barrier

    // per-lane B base pointers for the 7 N-fragments
    const unsigned short* bbase[7];
    #pragma unroll
    for (int ni = 0; ni < 7; ++ni) {
        int c  = ni * 16 + r;
        int hr = (c >= 56) ? 1 : 0;
        int lo = hr * (16 * CH) + (c - hr * 56);
        bbase[ni] = &ldsB[(size_t)((wn * 32 + g) * CH + lo) * 8];
    }

    f32x4 acc[4][7];
    #pragma unroll
    for (int mi = 0; mi < 4; ++mi)
        #pragma unroll
        for (int ni = 0; ni < 7; ++ni)
            #pragma unroll
            for (int v = 0; v < 4; ++v) acc[mi][ni][v] = 0.f;

    const unsigned short* aread = aslot + lane * 8;   // + slot*2048 + mi*512

    // ---- distance-1 B-register double-buffer ----
    short8 bcur[7], bnxt[7];
    #define LOAD_B(dst, s_)                                                     \
        {                                                                       \
            const int t_ = (s_) >> 2, cc_ = (s_) & 3;                           \
            const int kh_ = t_ / 3, kw_ = t_ - 3 * (t_ / 3);                    \
            const int boff_ = kh_ * 15104 + cc_ * 3776 + kw_ * 16;              \
            _Pragma("unroll")                                                   \
            for (int ni = 0; ni < 7; ++ni)                                      \
                dst[ni] = *(const short8*)((const char*)bbase[ni] + boff_);     \
        }

    LOAD_B(bcur, 0);

    #pragma unroll
    for (int s = 0; s < 36; ++s) {
        const int p = s & 1;

        if (s < 35) STAGE_A(p ^ 1, s + 1);      // next A slice (async glds)
        if (s < 35) {                           // next B frags (ds_reads issue
            if (p == 0) { LOAD_B(bnxt, s + 1); }//  before this step's MFMAs)
            else        { LOAD_B(bcur, s + 1); }
        }

        // wait: step-s's 4 glds landed (s+1's 4 may stay in flight)
        if (s < 35) asm volatile("s_waitcnt vmcnt(4)" ::: "memory");
        else        asm volatile("s_waitcnt vmcnt(0)" ::: "memory");

        short8 a[4];
        #pragma unroll
        for (int mi = 0; mi < 4; ++mi)
            a[mi] = *(const short8*)(aread + p * 2048 + mi * 512);

        #pragma unroll
        for (int mi = 0; mi < 4; ++mi)
            #pragma unroll
            for (int ni = 0; ni < 7; ++ni)
                acc[mi][ni] = __builtin_amdgcn_mfma_f32_16x16x32_bf16(
                    a[mi], (p == 0) ? bcur[ni] : bnxt[ni], acc[mi][ni], 0, 0, 0);
    }

    // ---- epilogue: D col = r (spatial), row = g*4+v (Cout within frag) ----
    #pragma unroll
    for (int mi = 0; mi < 4; ++mi) {
        const int o0 = wm * 64 + mi * 16 + 4 * g;
        const float4 bv = *(const float4*)&bias[o0];
        #pragma unroll
        for (int ni = 0; ni < 7; ++ni) {
            const int c  = ni * 16 + r;
            const int hr = (c >= 56) ? 1 : 0;
            const int h  = h0 + wn * 2 + hr;
            const int w  = c - hr * 56;
            #pragma unroll
            for (int v = 0; v < 4; ++v) {
                out[((size_t)(n * COUT + o0 + v) * HH + h) * WW + w] =
                    acc[mi][ni][v] + ((const float*)&bv)[v];
            }
        }
    }
}

extern "C" void kernel_launch(void* const* d_in, const int* in_sizes, int n_in,
                              void* d_out, int out_size, void* d_ws, size_t ws_size,
                              hipStream_t stream) {
    const float* x  = (const float*)d_in[0];   // (32,128,56,56)
    const float* wk = (const float*)d_in[1];   // (256,128,3,3)
    const float* b  = (const float*)d_in[2];   // (256,)
    float* out = (float*)d_out;

    unsigned short* wt2 = (unsigned short*)d_ws;   // 294,912 elems = 590 KB

    wpose_kernel<<<(36 * 16 * 64 * 8 + 255) / 256, 256, 0, stream>>>(wk, wt2);
    conv_mfma_kernel<<<448, 512, 0, stream>>>(x, wt2, b, out);
    (void)ws_size; (void)in_sizes; (void)n_in; (void)out_size;
}

// Round 25
// 69.442 us; speedup vs baseline: 1.0661x; 1.0132x over previous
//
#include <hip/hip_runtime.h>
#include <hip/hip_bf16.h>

#define NB   32
#define CIN  128
#define COUT 256
#define HH   56
#define WW   56
#define CH   59        // padded B-row length in 16B chunks (944 = 16*59)

typedef __attribute__((ext_vector_type(8))) short short8;   // 8 bf16 (4 VGPRs)
typedef __attribute__((ext_vector_type(4))) float f32x4;    // MFMA accumulator

// round-to-nearest-even fp32 -> bf16 (raw u16)
__device__ __forceinline__ unsigned short f2bf(float f) {
    unsigned int u = __builtin_bit_cast(unsigned int, f);
    u = u + 0x7fffu + ((u >> 16) & 1u);
    return (unsigned short)(u >> 16);
}

// async global->LDS, 16B per lane; LDS dest = wave-uniform base + lane*16
__device__ __forceinline__ void glds16(const unsigned short* g, unsigned short* l) {
    __builtin_amdgcn_global_load_lds(
        (const __attribute__((address_space(1))) unsigned int*)g,
        (__attribute__((address_space(3))) unsigned int*)l,
        16, 0, 0);
}

// ---------------------------------------------------------------------------
// Pre-pass (scalar form -- measured best vs two LDS-staged rewrites):
// weights OIHW f32 -> wt2 in EXACT MFMA A-fragment order:
//   chunk ((s*16 + f)*64 + lane), elem j:  w[o=f*16+r][c=cc*32+g*8+j][tap t]
// Linear output q -> perfectly coalesced 2B stores; strided reads L2-absorbed;
// 1152 blocks = full-machine TLP (parallelism beats coalescing here).
// ---------------------------------------------------------------------------
__global__ __launch_bounds__(256) void wpose_kernel(const float* __restrict__ w,
                                                    unsigned short* __restrict__ wt2) {
    int q = blockIdx.x * 256 + threadIdx.x;
    if (q >= 36 * 16 * 64 * 8) return;
    int j = q & 7;
    int l = (q >> 3) & 63;
    int f = (q >> 9) & 15;
    int s = q >> 13;
    int g = l >> 4, r = l & 15;
    int t = s >> 2, cc = s & 3;
    int o = f * 16 + r;
    int c = cc * 32 + g * 8 + j;
    wt2[q] = f2bf(w[((size_t)o * CIN + c) * 9 + t]);
}

// ---------------------------------------------------------------------------
// Main conv (= r24 measured-best + A-REGISTER double-buffer):
// block = 256 Cout x 224 spatial (4 output rows h0..h0+3), 512 threads =
// 8 waves as 4(M) x 2(N); wave = 64 Cout x 112 cols (4 M-frags x 7 N-frags
// of 16x16x32 -- the unique port-balanced point at 2 waves/SIMD).
// 36 K-steps, barrier-free.
//
// NEW vs r24: the vmcnt wait + A ds_reads for step s+1 are moved to the END
// of step s (after its MFMAs), so every step's MFMA burst starts on
// registers only -- the ~120-250 cyc in-step ds_read/vmcnt latency that
// capped MfmaUtil at 30% moves off the critical path. Ring stays 2-slot;
// stage s+2 is issued into slot p right after step s consumed it.
//
// T1 swizzle: 1-D grid of 448 (= 8*56 -> bijective); XCD d%8 gets 56
// consecutive tiles = 4 complete images (FETCH 43.2 -> 30.2 MB measured).
//   A: per-wave private LDS ring (2 slots x 4 frags) fed by global_load_lds,
//      ordered by per-wave counted vmcnt only -- NO s_barrier.
//   B: x rows h0-1..h0+4 transposed in-block, float4-vectorized, staged ONCE;
//      pad-only zeroing; K-loop B addressing = 16-bit ds_read immediates;
//      distance-1 B-register double-buffer.
// LDS = 90624 (B) + 65536 (A-ring) = 156160 B.
// ---------------------------------------------------------------------------
__global__ __launch_bounds__(512, 2) void conv_mfma_kernel(
        const float* __restrict__ x,
        const unsigned short* __restrict__ wt2,
        const float* __restrict__ bias,
        float* __restrict__ out) {
    __shared__ unsigned short ldsB[6 * 16 * CH * 8];    // 90624 B
    __shared__ unsigned short ldsA[8 * 2 * 2048];       // 65536 B: [wave][slot][4KB]

    const int tid  = threadIdx.x;
    // ---- XCD-chunked bijective swizzle (448 = 8 XCDs x 56 tiles) ----
    const int bid  = blockIdx.x;
    const int swz  = (bid & 7) * 56 + (bid >> 3);
    const int n    = swz / 14;
    const int h0   = (swz - n * 14) * 4;
    const int wid  = tid >> 6, lane = tid & 63;
    const int wm   = wid >> 1, wn = wid & 1;            // 4M x 2N wave grid
    const int g    = lane >> 4, r = lane & 15;

    const uint4 z = {0u, 0u, 0u, 0u};

    // ---- zero ONLY pad chunks (wpos 0,57,58 all rows) + OOB rows ----
    if (tid < 288) {                        // 6 rows x 16 gc x {0,57,58}
        int row = tid / 48, sub = tid % 48;
        int gc = sub / 3, k3 = sub % 3;
        int wp = (k3 == 0) ? 0 : (56 + k3);
        *(uint4*)&ldsB[(size_t)((row * 16 + gc) * CH + wp) * 8] = z;
    }
    if (h0 == 0) {                          // input row h0-1 OOB -> row 0 = 0
        for (int i = tid; i < 16 * CH; i += 512)
            *(uint4*)&ldsB[(size_t)i * 8] = z;
    }
    if (h0 == 52) {                         // input row h0+4 OOB -> row 5 = 0
        for (int i = tid; i < 16 * CH; i += 512)
            *(uint4*)&ldsB[(size_t)(5 * 16 * CH + i) * 8] = z;
    }

    // ---- fused transpose, float4-vectorized: unit = (row, cp, w4) ----
    {
        const float* xn = x + (size_t)n * CIN * HH * WW;
        for (int i = tid; i < 6 * 64 * 14; i += 512) {   // 5376 units
            int w4  = i % 14;
            int t1  = i / 14;
            int cp  = t1 & 63;                  // channel pair: c = 2cp, 2cp+1
            int row = t1 >> 6;                  // 0..5 -> input row h0+row-1
            int hs  = h0 + row - 1;
            if ((unsigned)hs < HH) {
                const float* p = xn + ((size_t)(2 * cp) * HH + hs) * WW + 4 * w4;
                float4 va = *(const float4*)p;
                float4 vb = *(const float4*)(p + HH * WW);
                int gc = cp >> 2, e = cp & 3;
                #pragma unroll
                for (int j = 0; j < 4; ++j) {
                    int wpos = 4 * w4 + j + 1;
                    unsigned int pk = (unsigned int)f2bf(((const float*)&va)[j])
                                    | ((unsigned int)f2bf(((const float*)&vb)[j]) << 16);
                    ((unsigned int*)ldsB)[((row * 16 + gc) * CH + wpos) * 4 + e] = pk;
                }
            }
        }
    }

    // ---- A-ring stage: wave wid's 4 frags (f = wm*4+mi) for step s -> slot ----
    unsigned short* aslot = &ldsA[(size_t)wid * 2 * 2048];
    #define STAGE_A(slot, s)                                                    \
        {                                                                       \
            const unsigned short* asrc_ =                                       \
                wt2 + ((size_t)(s) * 16 + wm * 4) * 512 + lane * 8;             \
            unsigned short* adst_ = aslot + (slot) * 2048;                      \
            glds16(asrc_,        adst_);                                        \
            glds16(asrc_ + 512,  adst_ + 512);                                  \
            glds16(asrc_ + 1024, adst_ + 1024);                                 \
            glds16(asrc_ + 1536, adst_ + 1536);                                 \
        }

    STAGE_A(0, 0);
    __syncthreads();    // drains transpose writes AND slot-0 glds; last barrier

    // per-lane B base pointers for the 7 N-fragments
    const unsigned short* bbase[7];
    #pragma unroll
    for (int ni = 0; ni < 7; ++ni) {
        int c  = ni * 16 + r;
        int hr = (c >= 56) ? 1 : 0;
        int lo = hr * (16 * CH) + (c - hr * 56);
        bbase[ni] = &ldsB[(size_t)((wn * 32 + g) * CH + lo) * 8];
    }

    f32x4 acc[4][7];
    #pragma unroll
    for (int mi = 0; mi < 4; ++mi)
        #pragma unroll
        for (int ni = 0; ni < 7; ++ni)
            #pragma unroll
            for (int v = 0; v < 4; ++v) acc[mi][ni][v] = 0.f;

    const unsigned short* aread = aslot + lane * 8;   // + slot*2048 + mi*512

    // ---- distance-1 register double-buffers for BOTH operands ----
    short8 aA[4], aB[4], bA[7], bB[7];

    #define LOAD_A(dst, slot)                                                   \
        {                                                                       \
            _Pragma("unroll")                                                   \
            for (int mi = 0; mi < 4; ++mi)                                      \
                dst[mi] = *(const short8*)(aread + (slot) * 2048 + mi * 512);   \
        }

    #define LOAD_B(dst, s_)                                                     \
        {                                                                       \
            const int t_ = (s_) >> 2, cc_ = (s_) & 3;                           \
            const int kh_ = t_ / 3, kw_ = t_ - 3 * (t_ / 3);                    \
            const int boff_ = kh_ * 15104 + cc_ * 3776 + kw_ * 16;              \
            _Pragma("unroll")                                                   \
            for (int ni = 0; ni < 7; ++ni)                                      \
                dst[ni] = *(const short8*)((const char*)bbase[ni] + boff_);     \
        }

    LOAD_A(aA, 0);      // slot 0 landed (drained by the barrier)
    LOAD_B(bA, 0);
    STAGE_A(1, 1);      // stage s+1 flies across step 0

    #pragma unroll
    for (int s = 0; s < 36; ++s) {
        const int p = s & 1;

        // B-regs for s+1: ds_reads issue before the MFMAs, consumed at s+1
        if (s < 35) {
            if (p == 0) { LOAD_B(bB, s + 1); } else { LOAD_B(bA, s + 1); }
        }

        // MFMA burst: all operands already in registers (loaded at s-1)
        #pragma unroll
        for (int mi = 0; mi < 4; ++mi)
            #pragma unroll
            for (int ni = 0; ni < 7; ++ni)
                acc[mi][ni] = __builtin_amdgcn_mfma_f32_16x16x32_bf16(
                    (p == 0) ? aA[mi] : aB[mi],
                    (p == 0) ? bA[ni] : bB[ni], acc[mi][ni], 0, 0, 0);

        // end-of-step: issue stage s+2 into the slot just consumed (p),
        // wait stage s+1 (has had a full step to land), prefetch its a-regs
        if (s < 35) {
            if (s + 2 <= 35) {
                STAGE_A(p, s + 2);
                asm volatile("s_waitcnt vmcnt(4)" ::: "memory");
            } else {
                asm volatile("s_waitcnt vmcnt(0)" ::: "memory");
            }
            if (p == 0) { LOAD_A(aB, (s + 1) & 1); }
            else        { LOAD_A(aA, (s + 1) & 1); }
        }
    }

    // ---- epilogue: D col = r (spatial), row = g*4+v (Cout within frag) ----
    #pragma unroll
    for (int mi = 0; mi < 4; ++mi) {
        const int o0 = wm * 64 + mi * 16 + 4 * g;
        const float4 bv = *(const float4*)&bias[o0];
        #pragma unroll
        for (int ni = 0; ni < 7; ++ni) {
            const int c  = ni * 16 + r;
            const int hr = (c >= 56) ? 1 : 0;
            const int h  = h0 + wn * 2 + hr;
            const int w  = c - hr * 56;
            #pragma unroll
            for (int v = 0; v < 4; ++v) {
                out[((size_t)(n * COUT + o0 + v) * HH + h) * WW + w] =
                    acc[mi][ni][v] + ((const float*)&bv)[v];
            }
        }
    }
}

extern "C" void kernel_launch(void* const* d_in, const int* in_sizes, int n_in,
                              void* d_out, int out_size, void* d_ws, size_t ws_size,
                              hipStream_t stream) {
    const float* x  = (const float*)d_in[0];   // (32,128,56,56)
    const float* wk = (const float*)d_in[1];   // (256,128,3,3)
    const float* b  = (const float*)d_in[2];   // (256,)
    float* out = (float*)d_out;

    unsigned short* wt2 = (unsigned short*)d_ws;   // 294,912 elems = 590 KB

    wpose_kernel<<<(36 * 16 * 64 * 8 + 255) / 256, 256, 0, stream>>>(wk, wt2);
    conv_mfma_kernel<<<448, 512, 0, stream>>>(x, wt2, b, out);
    (void)ws_size; (void)in_sizes; (void)n_in; (void)out_size;
}

// Round 26
// 67.888 us; speedup vs baseline: 1.0905x; 1.0229x over previous
//
#include <hip/hip_runtime.h>
#include <hip/hip_bf16.h>

#define NB   32
#define CIN  128
#define COUT 256
#define HH   56
#define WW   56
#define CH   59        // padded B-row length in 16B chunks (944 = 16*59)

typedef __attribute__((ext_vector_type(8))) short short8;   // 8 bf16 (4 VGPRs)
typedef __attribute__((ext_vector_type(4))) float f32x4;    // MFMA accumulator

// round-to-nearest-even fp32 -> bf16 (raw u16)
__device__ __forceinline__ unsigned short f2bf(float f) {
    unsigned int u = __builtin_bit_cast(unsigned int, f);
    u = u + 0x7fffu + ((u >> 16) & 1u);
    return (unsigned short)(u >> 16);
}

// ---------------------------------------------------------------------------
// Pre-pass (scalar form -- measured best vs two LDS-staged rewrites):
// weights OIHW f32 -> wt2 in EXACT MFMA A-fragment order:
//   chunk ((s*16 + f)*64 + lane), elem j:  w[o=f*16+r][c=cc*32+g*8+j][tap t]
// Linear output q -> perfectly coalesced 2B stores; strided reads L2-absorbed;
// 1152 blocks = full-machine TLP (parallelism beats coalescing here).
// ---------------------------------------------------------------------------
__global__ __launch_bounds__(256) void wpose_kernel(const float* __restrict__ w,
                                                    unsigned short* __restrict__ wt2) {
    int q = blockIdx.x * 256 + threadIdx.x;
    if (q >= 36 * 16 * 64 * 8) return;
    int j = q & 7;
    int l = (q >> 3) & 63;
    int f = (q >> 9) & 15;
    int s = q >> 13;
    int g = l >> 4, r = l & 15;
    int t = s >> 2, cc = s & 3;
    int o = f * 16 + r;
    int c = cc * 32 + g * 8 + j;
    wt2[q] = f2bf(w[((size_t)o * CIN + c) * 9 + t]);
}

// ---------------------------------------------------------------------------
// Main conv (= r25 + A-path direct global -> register double-buffer):
// block = 256 Cout x 224 spatial (4 output rows h0..h0+3), 512 threads =
// 8 waves as 4(M) x 2(N); wave = 64 Cout x 112 cols (4 M-frags x 7 N-frags
// of 16x16x32 -- the unique port-balanced point at 2 waves/SIMD).
// 36 K-steps, barrier-free (single barrier total).
//
// NEW vs r25: A-LDS ring DELETED. r25's port accounting showed the K-loop
// LDS traffic (~120 KB/step: 56 B-read + 32 A-read + 32 glds-write, with
// the A-ring staged redundantly per wm-pair) is the binding port. A-frags
// now load global->register (L1/L2-resident wt2, 8 KB/step/CU unique),
// prefetched distance-1 at END of the previous step so the ~200 cyc L1
// latency hides under the 28-MFMA burst (the lever r25 proved; r18's
// in-step direct-global variant lacked it and lost 4 us). LDS traffic
// drops to B's 56 KB/step; all vmcnt asm gone (compiler waitcnts).
//
// T1 swizzle: 1-D grid of 448 (= 8*56 -> bijective); XCD d%8 gets 56
// consecutive tiles = 4 complete images (FETCH 43.2 -> 30.2 MB measured).
//   B: x rows h0-1..h0+4 transposed in-block, float4-vectorized, staged ONCE;
//      pad-only zeroing; K-loop B addressing = 16-bit ds_read immediates;
//      distance-1 B-register double-buffer.
// LDS = 90624 B.
// ---------------------------------------------------------------------------
__global__ __launch_bounds__(512, 2) void conv_mfma_kernel(
        const float* __restrict__ x,
        const unsigned short* __restrict__ wt2,
        const float* __restrict__ bias,
        float* __restrict__ out) {
    __shared__ unsigned short ldsB[6 * 16 * CH * 8];    // 90624 B

    const int tid  = threadIdx.x;
    // ---- XCD-chunked bijective swizzle (448 = 8 XCDs x 56 tiles) ----
    const int bid  = blockIdx.x;
    const int swz  = (bid & 7) * 56 + (bid >> 3);
    const int n    = swz / 14;
    const int h0   = (swz - n * 14) * 4;
    const int wid  = tid >> 6, lane = tid & 63;
    const int wm   = wid >> 1, wn = wid & 1;            // 4M x 2N wave grid
    const int g    = lane >> 4, r = lane & 15;

    const uint4 z = {0u, 0u, 0u, 0u};

    // ---- zero ONLY pad chunks (wpos 0,57,58 all rows) + OOB rows ----
    if (tid < 288) {                        // 6 rows x 16 gc x {0,57,58}
        int row = tid / 48, sub = tid % 48;
        int gc = sub / 3, k3 = sub % 3;
        int wp = (k3 == 0) ? 0 : (56 + k3);
        *(uint4*)&ldsB[(size_t)((row * 16 + gc) * CH + wp) * 8] = z;
    }
    if (h0 == 0) {                          // input row h0-1 OOB -> row 0 = 0
        for (int i = tid; i < 16 * CH; i += 512)
            *(uint4*)&ldsB[(size_t)i * 8] = z;
    }
    if (h0 == 52) {                         // input row h0+4 OOB -> row 5 = 0
        for (int i = tid; i < 16 * CH; i += 512)
            *(uint4*)&ldsB[(size_t)(5 * 16 * CH + i) * 8] = z;
    }

    // ---- fused transpose, float4-vectorized: unit = (row, cp, w4) ----
    {
        const float* xn = x + (size_t)n * CIN * HH * WW;
        for (int i = tid; i < 6 * 64 * 14; i += 512) {   // 5376 units
            int w4  = i % 14;
            int t1  = i / 14;
            int cp  = t1 & 63;                  // channel pair: c = 2cp, 2cp+1
            int row = t1 >> 6;                  // 0..5 -> input row h0+row-1
            int hs  = h0 + row - 1;
            if ((unsigned)hs < HH) {
                const float* p = xn + ((size_t)(2 * cp) * HH + hs) * WW + 4 * w4;
                float4 va = *(const float4*)p;
                float4 vb = *(const float4*)(p + HH * WW);
                int gc = cp >> 2, e = cp & 3;
                #pragma unroll
                for (int j = 0; j < 4; ++j) {
                    int wpos = 4 * w4 + j + 1;
                    unsigned int pk = (unsigned int)f2bf(((const float*)&va)[j])
                                    | ((unsigned int)f2bf(((const float*)&vb)[j]) << 16);
                    ((unsigned int*)ldsB)[((row * 16 + gc) * CH + wpos) * 4 + e] = pk;
                }
            }
        }
    }
    __syncthreads();    // B ready; the only barrier

    // per-lane B base pointers for the 7 N-fragments
    const unsigned short* bbase[7];
    #pragma unroll
    for (int ni = 0; ni < 7; ++ni) {
        int c  = ni * 16 + r;
        int hr = (c >= 56) ? 1 : 0;
        int lo = hr * (16 * CH) + (c - hr * 56);
        bbase[ni] = &ldsB[(size_t)((wn * 32 + g) * CH + lo) * 8];
    }

    f32x4 acc[4][7];
    #pragma unroll
    for (int mi = 0; mi < 4; ++mi)
        #pragma unroll
        for (int ni = 0; ni < 7; ++ni)
            #pragma unroll
            for (int v = 0; v < 4; ++v) acc[mi][ni][v] = 0.f;

    // wave's A base: fragment f = wm*4 + mi, chunk ((s*16+f)*64 + lane)
    const short8* abase = (const short8*)wt2 + (size_t)(wm * 4) * 64 + lane;

    // ---- distance-1 register double-buffers for BOTH operands ----
    short8 aA[4], aB[4], bA[7], bB[7];

    #define LOAD_AG(dst, s_)                                                    \
        {                                                                       \
            _Pragma("unroll")                                                   \
            for (int mi = 0; mi < 4; ++mi)                                      \
                dst[mi] = abase[(size_t)(s_) * 1024 + mi * 64];                 \
        }

    #define LOAD_B(dst, s_)                                                     \
        {                                                                       \
            const int t_ = (s_) >> 2, cc_ = (s_) & 3;                           \
            const int kh_ = t_ / 3, kw_ = t_ - 3 * (t_ / 3);                    \
            const int boff_ = kh_ * 15104 + cc_ * 3776 + kw_ * 16;              \
            _Pragma("unroll")                                                   \
            for (int ni = 0; ni < 7; ++ni)                                      \
                dst[ni] = *(const short8*)((const char*)bbase[ni] + boff_);     \
        }

    LOAD_AG(aA, 0);
    LOAD_B(bA, 0);

    #pragma unroll
    for (int s = 0; s < 36; ++s) {
        const int p = s & 1;

        // prefetch step s+1 operands: globals first (longest latency), then
        // ds_reads; both consumed only at s+1 -> full MFMA burst to hide
        if (s < 35) {
            if (p == 0) { LOAD_AG(aB, s + 1); LOAD_B(bB, s + 1); }
            else        { LOAD_AG(aA, s + 1); LOAD_B(bA, s + 1); }
        }

        // MFMA burst: operands loaded one step ago, already in registers
        #pragma unroll
        for (int mi = 0; mi < 4; ++mi)
            #pragma unroll
            for (int ni = 0; ni < 7; ++ni)
                acc[mi][ni] = __builtin_amdgcn_mfma_f32_16x16x32_bf16(
                    (p == 0) ? aA[mi] : aB[mi],
                    (p == 0) ? bA[ni] : bB[ni], acc[mi][ni], 0, 0, 0);
    }

    // ---- epilogue: D col = r (spatial), row = g*4+v (Cout within frag) ----
    #pragma unroll
    for (int mi = 0; mi < 4; ++mi) {
        const int o0 = wm * 64 + mi * 16 + 4 * g;
        const float4 bv = *(const float4*)&bias[o0];
        #pragma unroll
        for (int ni = 0; ni < 7; ++ni) {
            const int c  = ni * 16 + r;
            const int hr = (c >= 56) ? 1 : 0;
            const int h  = h0 + wn * 2 + hr;
            const int w  = c - hr * 56;
            #pragma unroll
            for (int v = 0; v < 4; ++v) {
                out[((size_t)(n * COUT + o0 + v) * HH + h) * WW + w] =
                    acc[mi][ni][v] + ((const float*)&bv)[v];
            }
        }
    }
}

extern "C" void kernel_launch(void* const* d_in, const int* in_sizes, int n_in,
                              void* d_out, int out_size, void* d_ws, size_t ws_size,
                              hipStream_t stream) {
    const float* x  = (const float*)d_in[0];   // (32,128,56,56)
    const float* wk = (const float*)d_in[1];   // (256,128,3,3)
    const float* b  = (const float*)d_in[2];   // (256,)
    float* out = (float*)d_out;

    unsigned short* wt2 = (unsigned short*)d_ws;   // 294,912 elems = 590 KB

    wpose_kernel<<<(36 * 16 * 64 * 8 + 255) / 256, 256, 0, stream>>>(wk, wt2);
    conv_mfma_kernel<<<448, 512, 0, stream>>>(x, wt2, b, out);
    (void)ws_size; (void)in_sizes; (void)n_in; (void)out_size;
}